// Round 1
// baseline (14038.347 us; speedup 1.0000x reference)
//
#include <hip/hip_runtime.h>
#include <math.h>

#define BB   32     // batch
#define HH   1024   // hidden
#define TT   100    // time steps
#define KC   128    // k-chunk
#define NCH  (HH / KC)
#define LDSW 132    // KC + 4 pad (words per LDS row)

struct StepArgs {
    const float* x0;    // input rows (B rows, stride x0s elements)
    int x0s;
    const float* Wih;   // (4H, H)
    const float* Whh;   // (4H, H)
    const float* bsum;  // (4H) = b_ih + b_hh
    const float* h_in;  // (B,H)
    float* h_out;       // (B,H)
    float* c;           // (B,H), in/out
    float* out2;        // optional extra output (row stride out2s), may be null
    int out2s;
    int active;
};

__global__ __launch_bounds__(256) void bias_sum_kernel(
    const float* bih0, const float* bhh0, const float* bih1, const float* bhh1,
    float* bsum0, float* bsum1)
{
    int i = blockIdx.x * blockDim.x + threadIdx.x;
    if (i < 4096)       bsum0[i] = bih0[i] + bhh0[i];
    else if (i < 8192)  bsum1[i - 4096] = bih1[i - 4096] + bhh1[i - 4096];
}

// One pipelined step: role 0 = layer0@t, role 1 = layer1@(t-1).
// Per WG: 8 h-indices -> 32 gate rows x 32 batches, dual dot (x*Wih + h*Whh), K=1024 each.
__global__ __launch_bounds__(256) void lstm_step(StepArgs A0, StepArgs A1)
{
    const int role = blockIdx.x >> 7;
    const StepArgs a = role ? A1 : A0;
    if (!a.active) return;
    const int wg = blockIdx.x & 127;
    const int j0 = wg * 8;

    __shared__ float lds[2 * BB * LDSW];   // x tile, h tile; reused for partials
    float* part = lds;                     // [4][32][33]

    const int tid = threadIdx.x;
    const int g   = tid >> 6;      // k-group (one wave each)
    const int lam = tid & 63;
    const int bb  = lam >> 3;      // b-block: batches 4*bb..4*bb+3
    const int rb  = lam & 7;       // row-block: local rows 4*rb..4*rb+3
    const int m   = g & 1;         // 0: (x, Wih)   1: (h, Whh)
    const int hf  = g >> 1;        // k-half of each chunk

    const float* Wmat = m ? a.Whh : a.Wih;
    const float* wrow[4];
#pragma unroll
    for (int j = 0; j < 4; ++j) {
        int lr   = 4 * rb + j;         // local row 0..31
        int gate = lr >> 3;
        int jj   = lr & 7;
        wrow[j] = Wmat + (size_t)(gate * HH + j0 + jj) * HH;
    }

    float acc[4][4];
#pragma unroll
    for (int i = 0; i < 4; ++i)
#pragma unroll
        for (int j = 0; j < 4; ++j) acc[i][j] = 0.f;

    for (int ch = 0; ch < NCH; ++ch) {
        const int k0 = ch * KC;
        __syncthreads();
        // stage x tile (0) and h tile (1), swizzled k-quads
#pragma unroll
        for (int i = 0; i < 8; ++i) {
            int idx  = tid + i * 256;        // 0..2047
            int tile = idx >> 10;
            int rem  = idx & 1023;
            int row  = rem >> 5;             // 0..31
            int q    = rem & 31;             // k-quad in chunk
            const float* src = tile ? (a.h_in + (size_t)row * HH)
                                    : (a.x0 + (size_t)row * a.x0s);
            float4 v = *(const float4*)(src + k0 + 4 * q);
            *(float4*)&lds[(tile * BB + row) * LDSW + 4 * (q ^ (row & 7))] = v;
        }
        __syncthreads();

        const float* tbase = &lds[(m * BB) * LDSW];
#pragma unroll 4
        for (int kq = 0; kq < 16; ++kq) {
            int kqg = hf * 16 + kq;          // k-quad within chunk
            float4 xv[4], wv[4];
#pragma unroll
            for (int i = 0; i < 4; ++i) {
                int row = 4 * bb + i;
                xv[i] = *(const float4*)(tbase + row * LDSW + 4 * (kqg ^ (row & 7)));
            }
            int koff = k0 + 4 * kqg;
#pragma unroll
            for (int j = 0; j < 4; ++j)
                wv[j] = *(const float4*)(wrow[j] + koff);
#pragma unroll
            for (int i = 0; i < 4; ++i)
#pragma unroll
                for (int j = 0; j < 4; ++j)
                    acc[i][j] += xv[i].x * wv[j].x + xv[i].y * wv[j].y
                               + xv[i].z * wv[j].z + xv[i].w * wv[j].w;
        }
    }

    __syncthreads();
#pragma unroll
    for (int i = 0; i < 4; ++i)
#pragma unroll
        for (int j = 0; j < 4; ++j)
            part[(g * BB + (4 * bb + i)) * 33 + (4 * rb + j)] = acc[i][j];
    __syncthreads();

    // epilogue: thread -> (batch, jj)
    const int b  = tid >> 3;
    const int jj = tid & 7;
    float gate[4];
#pragma unroll
    for (int gg = 0; gg < 4; ++gg) {
        int r = gg * 8 + jj;
        float s = 0.f;
#pragma unroll
        for (int p = 0; p < 4; ++p) s += part[(p * BB + b) * 33 + r];
        gate[gg] = s + a.bsum[gg * HH + j0 + jj];
    }
    const int col = j0 + jj;
    float cv  = a.c[b * HH + col];
    float ig  = 1.f / (1.f + expf(-gate[0]));
    float fg  = 1.f / (1.f + expf(-gate[1]));
    float gg_ = tanhf(gate[2]);
    float og  = 1.f / (1.f + expf(-gate[3]));
    float cn  = fg * cv + ig * gg_;
    float hn  = og * tanhf(cn);
    a.c[b * HH + col]     = cn;
    a.h_out[b * HH + col] = hn;
    if (a.out2) a.out2[(size_t)b * a.out2s + col] = hn;
}

extern "C" void kernel_launch(void* const* d_in, const int* in_sizes, int n_in,
                              void* d_out, int out_size, void* d_ws, size_t ws_size,
                              hipStream_t stream)
{
    const float* X    = (const float*)d_in[0];   // (B,T,H)
    const float* Tg   = (const float*)d_in[1];   // targets (B,T,H)
    const float* Wih0 = (const float*)d_in[2];
    const float* Whh0 = (const float*)d_in[3];
    const float* bih0 = (const float*)d_in[4];
    const float* bhh0 = (const float*)d_in[5];
    const float* Wih1 = (const float*)d_in[6];
    const float* Whh1 = (const float*)d_in[7];
    const float* bih1 = (const float*)d_in[8];
    const float* bhh1 = (const float*)d_in[9];
    float* out = (float*)d_out;

    const int SZ = BB * HH;                       // 32768
    float* ws    = (float*)d_ws;
    float* h0p[2]; float* h1p[2];
    h0p[0] = ws;            h1p[0] = ws + SZ;
    float* c0 = ws + 2 * SZ; float* c1 = ws + 3 * SZ;
    h0p[1] = ws + 4 * SZ;   h1p[1] = ws + 5 * SZ;
    float* bsum0 = ws + 6 * SZ;
    float* bsum1 = bsum0 + 4096;

    // zero initial states: h0p[0], h1p[0], c0, c1 (contiguous)
    hipMemsetAsync(ws, 0, (size_t)4 * SZ * sizeof(float), stream);
    bias_sum_kernel<<<32, 256, 0, stream>>>(bih0, bhh0, bih1, bhh1, bsum0, bsum1);

    const int XS = TT * HH;    // row stride within (B,T,H)

    auto make = [&](const float* x0, int x0s, const float* Wih, const float* Whh,
                    const float* bsum, const float* h_in, float* h_out, float* c,
                    float* out2, int out2s, int active) {
        StepArgs s; s.x0 = x0; s.x0s = x0s; s.Wih = Wih; s.Whh = Whh; s.bsum = bsum;
        s.h_in = h_in; s.h_out = h_out; s.c = c; s.out2 = out2; s.out2s = out2s;
        s.active = active; return s;
    };

    // ---------------- encoder ----------------
    for (int t = 0; t <= TT; ++t) {
        StepArgs a0 = make(X + (size_t)t * HH, XS, Wih0, Whh0, bsum0,
                           h0p[t & 1], h0p[(t + 1) & 1], c0, nullptr, 0, t < TT);
        int u = t - 1;
        StepArgs a1 = make(h0p[t & 1], HH, Wih1, Whh1, bsum1,
                           h1p[u & 1], h1p[(u + 1) & 1], c1, nullptr, 0, t >= 1);
        lstm_step<<<256, 256, 0, stream>>>(a0, a1);
    }
    // after encoder: h0 final in h0p[0], h1 final ("last") in h1p[0], c0/c1 final.

    // ---------------- decoder (teacher forcing) ----------------
    for (int v = 0; v <= TT; ++v) {
        const float* x0 = (v == 0) ? h1p[0] : (Tg + (size_t)v * HH);
        int x0s         = (v == 0) ? HH : XS;
        StepArgs a0 = make(x0, x0s, Wih0, Whh0, bsum0,
                           h0p[v & 1], h0p[(v + 1) & 1], c0, nullptr, 0, v < TT);
        int u = v - 1;
        StepArgs a1 = make(h0p[v & 1], HH, Wih1, Whh1, bsum1,
                           h1p[u & 1], h1p[(u + 1) & 1], c1,
                           out + (size_t)u * HH, XS, v >= 1);
        lstm_step<<<256, 256, 0, stream>>>(a0, a1);
    }
}

// Round 2
// 2688.158 us; speedup vs baseline: 5.2223x; 5.2223x over previous
//
#include <hip/hip_runtime.h>
#include <math.h>

#define BB 32
#define HH 1024
#define TT 100
#define TH (TT * HH)

typedef __attribute__((ext_vector_type(8))) short short8;
typedef __attribute__((ext_vector_type(4))) float f32x4;

#define MFMA_BF16 __builtin_amdgcn_mfma_f32_16x16x32_bf16

__device__ __forceinline__ unsigned short bf16_rne(float f) {
    unsigned u = __builtin_bit_cast(unsigned, f);
    u += 0x7FFFu + ((u >> 16) & 1u);
    return (unsigned short)(u >> 16);
}
__device__ __forceinline__ float bf16_to_f(unsigned short h) {
    return __builtin_bit_cast(float, (unsigned)h << 16);
}

// ---------------- weight packing ----------------
// Wp layout (per layer): [hb 128][w 8][s 8][nt 2][lane 64][i 8] bf16
//   n_local = nt*16 + (lane&15); gate = n_local>>3; col = hb*8 + (n_local&7)
//   n = gate*1024 + col;  k = w*256 + s*32 + (lane>>4)*8 + i
//   src = k<1024 ? Wih[n][k] : Whh[n][k-1024]
__global__ __launch_bounds__(256) void pack_w(
    const float* __restrict__ Wih0, const float* __restrict__ Whh0,
    const float* __restrict__ Wih1, const float* __restrict__ Whh1,
    unsigned short* __restrict__ Wp0, unsigned short* __restrict__ Wp1)
{
    int id   = blockIdx.x * 256 + threadIdx.x;   // 0 .. 2^21-1
    int lane = id & 63;
    int nt   = (id >> 6) & 1;
    int s    = (id >> 7) & 7;
    int w    = (id >> 10) & 7;
    int hb   = (id >> 13) & 127;
    int layer = id >> 20;
    const float* Wih = layer ? Wih1 : Wih0;
    const float* Whh = layer ? Whh1 : Whh0;
    unsigned short* Wp = layer ? Wp1 : Wp0;

    int nl   = nt * 16 + (lane & 15);
    int gate = nl >> 3;
    int col  = hb * 8 + (nl & 7);
    int n    = gate * 1024 + col;
    int k    = w * 256 + s * 32 + ((lane >> 4) & 3) * 8;
    const float* src = (k < 1024) ? (Wih + (size_t)n * HH + k)
                                  : (Whh + (size_t)n * HH + (k - 1024));
    float4 v0 = *(const float4*)src;
    float4 v1 = *(const float4*)(src + 4);
    short8 d;
    d[0] = (short)bf16_rne(v0.x); d[1] = (short)bf16_rne(v0.y);
    d[2] = (short)bf16_rne(v0.z); d[3] = (short)bf16_rne(v0.w);
    d[4] = (short)bf16_rne(v1.x); d[5] = (short)bf16_rne(v1.y);
    d[6] = (short)bf16_rne(v1.z); d[7] = (short)bf16_rne(v1.w);
    *(short8*)(Wp + (size_t)(id & 0xFFFFF) * 8) = d;
}

__global__ __launch_bounds__(256) void bias_sum_kernel(
    const float* bih0, const float* bhh0, const float* bih1, const float* bhh1,
    float* bsum0, float* bsum1)
{
    int i = blockIdx.x * blockDim.x + threadIdx.x;
    if (i < 4096)      bsum0[i] = bih0[i] + bhh0[i];
    else if (i < 8192) bsum1[i - 4096] = bih1[i - 4096] + bhh1[i - 4096];
}

// ---------------- pipelined LSTM step ----------------
struct Role {
    const float* x_f32;            // fp32 x rows, stride xs (xmode 0)
    const unsigned short* x_hi;    // bf16 hi/lo rows, stride 1024 (xmode 1)
    const unsigned short* x_lo;
    int xs;
    int xmode;
    const unsigned short* Wp;
    const float* bsum;
    const unsigned short* h_hi;    // h_in hi/lo
    const unsigned short* h_lo;
    unsigned short* ho_hi;         // h_out hi/lo
    unsigned short* ho_lo;
    float* c;
    float* out2;                   // optional fp32 rows (stride out2s)
    long long out2s;
    int active;
};

// grid 256 x 512: blocks [0,128) layer-role0, [128,256) role1.
// Per WG: 32 gate rows (4 gates x 8 cols) x 32 batches, K=2048 split over 8 waves.
__global__ __launch_bounds__(512, 2) void lstm_step(Role R0, Role R1)
{
    const Role a = (blockIdx.x >= 128) ? R1 : R0;
    if (!a.active) return;
    const int hb   = blockIdx.x & 127;
    const int tid  = threadIdx.x;
    const int w    = tid >> 6;
    const int lane = tid & 63;
    const int lr   = lane & 15;       // A row / B col within tile
    const int lg   = lane >> 4;       // k-group (0..3)

    __shared__ float part[8][32][33];

    // weight stream base for this wave
    const unsigned short* wp = a.Wp + (size_t)hb * 65536 + (size_t)w * 8192 + (size_t)lane * 8;

    f32x4 acc[2][2] = {};
    const int kbase = w * 256 + lg * 8;

#pragma unroll
    for (int s = 0; s < 8; ++s) {
        const int kg = kbase + s * 32;
        short8 bA = *(const short8*)(wp + (size_t)s * 1024);
        short8 bB = *(const short8*)(wp + (size_t)s * 1024 + 512);
        short8 ahi[2], alo[2];
        if (w < 4) {   // x region (k < 1024), wave-uniform
            if (a.xmode == 0) {
#pragma unroll
                for (int mt = 0; mt < 2; ++mt) {
                    const float* p = a.x_f32 + (size_t)(16 * mt + lr) * a.xs + kg;
                    float4 v0 = *(const float4*)p;
                    float4 v1 = *(const float4*)(p + 4);
                    float fv[8] = {v0.x, v0.y, v0.z, v0.w, v1.x, v1.y, v1.z, v1.w};
#pragma unroll
                    for (int i = 0; i < 8; ++i) {
                        unsigned short h_ = bf16_rne(fv[i]);
                        float hf = bf16_to_f(h_);
                        ahi[mt][i] = (short)h_;
                        alo[mt][i] = (short)bf16_rne(fv[i] - hf);
                    }
                }
            } else {
#pragma unroll
                for (int mt = 0; mt < 2; ++mt) {
                    size_t base = (size_t)(16 * mt + lr) * HH + kg;
                    ahi[mt] = *(const short8*)(a.x_hi + base);
                    alo[mt] = *(const short8*)(a.x_lo + base);
                }
            }
        } else {       // h region
            const int kh = kg - 1024;
#pragma unroll
            for (int mt = 0; mt < 2; ++mt) {
                size_t base = (size_t)(16 * mt + lr) * HH + kh;
                ahi[mt] = *(const short8*)(a.h_hi + base);
                alo[mt] = *(const short8*)(a.h_lo + base);
            }
        }
#pragma unroll
        for (int mt = 0; mt < 2; ++mt) {
            acc[mt][0] = MFMA_BF16(ahi[mt], bA, acc[mt][0], 0, 0, 0);
            acc[mt][0] = MFMA_BF16(alo[mt], bA, acc[mt][0], 0, 0, 0);
            acc[mt][1] = MFMA_BF16(ahi[mt], bB, acc[mt][1], 0, 0, 0);
            acc[mt][1] = MFMA_BF16(alo[mt], bB, acc[mt][1], 0, 0, 0);
        }
    }

    // D layout: row = lg*4 + j (batch within tile), col = lr (n_local within tile)
#pragma unroll
    for (int mt = 0; mt < 2; ++mt)
#pragma unroll
        for (int nt = 0; nt < 2; ++nt)
#pragma unroll
            for (int j = 0; j < 4; ++j)
                part[w][16 * mt + lg * 4 + j][16 * nt + lr] = acc[mt][nt][j];
    __syncthreads();

    if (tid < 256) {
        const int b  = tid >> 3;
        const int cc = tid & 7;
        float g4[4];
#pragma unroll
        for (int gate = 0; gate < 4; ++gate) {
            const int nl = gate * 8 + cc;
            float sum = 0.f;
#pragma unroll
            for (int p = 0; p < 8; ++p) sum += part[p][b][nl];
            g4[gate] = sum + a.bsum[gate * 1024 + hb * 8 + cc];
        }
        const int col = hb * 8 + cc;
        float cv  = a.c[b * HH + col];
        float ig  = 1.f / (1.f + expf(-g4[0]));
        float fg  = 1.f / (1.f + expf(-g4[1]));
        float gg  = tanhf(g4[2]);
        float og  = 1.f / (1.f + expf(-g4[3]));
        float cn  = fg * cv + ig * gg;
        float hn  = og * tanhf(cn);
        a.c[b * HH + col] = cn;
        unsigned short hh = bf16_rne(hn);
        a.ho_hi[b * HH + col] = hh;
        a.ho_lo[b * HH + col] = bf16_rne(hn - bf16_to_f(hh));
        if (a.out2) a.out2[(size_t)b * a.out2s + col] = hn;
    }
}

extern "C" void kernel_launch(void* const* d_in, const int* in_sizes, int n_in,
                              void* d_out, int out_size, void* d_ws, size_t ws_size,
                              hipStream_t stream)
{
    const float* X    = (const float*)d_in[0];
    const float* Tg   = (const float*)d_in[1];
    const float* Wih0 = (const float*)d_in[2];
    const float* Whh0 = (const float*)d_in[3];
    const float* bih0 = (const float*)d_in[4];
    const float* bhh0 = (const float*)d_in[5];
    const float* Wih1 = (const float*)d_in[6];
    const float* Whh1 = (const float*)d_in[7];
    const float* bih1 = (const float*)d_in[8];
    const float* bhh1 = (const float*)d_in[9];
    float* out = (float*)d_out;

    const size_t SZH = (size_t)BB * HH * sizeof(unsigned short); // 64 KB
    const size_t SZF = (size_t)BB * HH * sizeof(float);          // 128 KB
    char* p = (char*)d_ws;
    // zero-init region (512 KB)
    unsigned short* h0hi[2]; unsigned short* h0lo[2];
    unsigned short* h1hi[2]; unsigned short* h1lo[2];
    h0hi[0] = (unsigned short*)p; p += SZH;
    h0lo[0] = (unsigned short*)p; p += SZH;
    h1hi[0] = (unsigned short*)p; p += SZH;
    h1lo[0] = (unsigned short*)p; p += SZH;
    float* c0 = (float*)p; p += SZF;
    float* c1 = (float*)p; p += SZF;
    const size_t zero_bytes = (size_t)(p - (char*)d_ws);
    h0hi[1] = (unsigned short*)p; p += SZH;
    h0lo[1] = (unsigned short*)p; p += SZH;
    h1hi[1] = (unsigned short*)p; p += SZH;
    h1lo[1] = (unsigned short*)p; p += SZH;
    float* bsum0 = (float*)p; p += 4096 * sizeof(float);
    float* bsum1 = (float*)p; p += 4096 * sizeof(float);
    unsigned short* Wp0 = (unsigned short*)p; p += (size_t)4096 * 2048 * sizeof(unsigned short);
    unsigned short* Wp1 = (unsigned short*)p;

    hipMemsetAsync(d_ws, 0, zero_bytes, stream);
    bias_sum_kernel<<<32, 256, 0, stream>>>(bih0, bhh0, bih1, bhh1, bsum0, bsum1);
    pack_w<<<8192, 256, 0, stream>>>(Wih0, Whh0, Wih1, Whh1, Wp0, Wp1);

    auto mk = [&](const float* xf, const unsigned short* xh, const unsigned short* xl,
                  int xs, int xmode, const unsigned short* Wp, const float* bsum,
                  const unsigned short* hhi, const unsigned short* hlo,
                  unsigned short* ohi, unsigned short* olo, float* c,
                  float* out2, long long out2s, int active) {
        Role r; r.x_f32 = xf; r.x_hi = xh; r.x_lo = xl; r.xs = xs; r.xmode = xmode;
        r.Wp = Wp; r.bsum = bsum; r.h_hi = hhi; r.h_lo = hlo; r.ho_hi = ohi;
        r.ho_lo = olo; r.c = c; r.out2 = out2; r.out2s = out2s; r.active = active;
        return r;
    };

    // ---------------- encoder ----------------
    for (int t = 0; t <= TT; ++t) {
        Role r0 = mk(X + (size_t)t * HH, nullptr, nullptr, TH, 0, Wp0, bsum0,
                     h0hi[t & 1], h0lo[t & 1], h0hi[(t + 1) & 1], h0lo[(t + 1) & 1],
                     c0, nullptr, 0, t < TT);
        int u = t - 1;
        Role r1 = mk(nullptr, h0hi[t & 1], h0lo[t & 1], HH, 1, Wp1, bsum1,
                     h1hi[u & 1], h1lo[u & 1], h1hi[t & 1], h1lo[t & 1],
                     c1, nullptr, 0, t >= 1);
        lstm_step<<<256, 512, 0, stream>>>(r0, r1);
    }
    // h0 final in h0hi/lo[0]; h1 final ("last") in h1hi/lo[0]

    // ---------------- decoder (teacher forcing) ----------------
    for (int v = 0; v <= TT; ++v) {
        Role r0 = (v == 0)
            ? mk(nullptr, h1hi[0], h1lo[0], HH, 1, Wp0, bsum0,
                 h0hi[0], h0lo[0], h0hi[1], h0lo[1], c0, nullptr, 0, 1)
            : mk(Tg + (size_t)v * HH, nullptr, nullptr, TH, 0, Wp0, bsum0,
                 h0hi[v & 1], h0lo[v & 1], h0hi[(v + 1) & 1], h0lo[(v + 1) & 1],
                 c0, nullptr, 0, v < TT);
        int u = v - 1;
        Role r1 = mk(nullptr, h0hi[v & 1], h0lo[v & 1], HH, 1, Wp1, bsum1,
                     h1hi[u & 1], h1lo[u & 1], h1hi[v & 1], h1lo[v & 1],
                     c1, out + (size_t)u * HH, (long long)TH, v >= 1);
        lstm_step<<<256, 512, 0, stream>>>(r0, r1);
    }
}